// Round 1
// baseline (168.761 us; speedup 1.0000x reference)
//
#include <hip/hip_runtime.h>
#include <math.h>

#define NROWS  65536      // B*T = 16*4096
#define DIM    64
#define KCODE  1024
#define MBLK   128        // rows per block (main)
#define KCHUNK 128        // codes per LDS strip
#define NSTRIP (KCODE / KCHUNK)   // 8
#define LDSW   68         // padded row stride in floats (16B-aligned, bank-staggered)
#define TAU    2e-3f      // fp32 margin below which we re-score in fp64

// ws layout (bytes):
//   [0     .. 4095 ]  float e2[1024]
//   [4096  .. 8191 ]  int   counts[1024]
//   [8192  .. 8195 ]  float sse
//   [8208  .. 73743]  unsigned char flags[NROWS]
#define WS_E2(ws)     ((float*)(ws))
#define WS_COUNTS(ws) ((int*)((char*)(ws) + 4096))
#define WS_SSE(ws)    ((float*)((char*)(ws) + 8192))
#define WS_FLAGS(ws)  ((unsigned char*)(ws) + 8208)

// ---------------------------------------------------------------- init ----
__global__ __launch_bounds__(256) void vq_init(const float* __restrict__ emb,
                                               void* ws) {
  int k = blockIdx.x * 256 + threadIdx.x;   // 0..1023
  if (k < KCODE) {
    const float4* e = (const float4*)(emb + k * DIM);
    float4 s = make_float4(0.f, 0.f, 0.f, 0.f);
#pragma unroll
    for (int t = 0; t < 16; ++t) {
      float4 v = e[t];
      s.x = fmaf(v.x, v.x, s.x); s.y = fmaf(v.y, v.y, s.y);
      s.z = fmaf(v.z, v.z, s.z); s.w = fmaf(v.w, v.w, s.w);
    }
    WS_E2(ws)[k] = (s.x + s.y) + (s.z + s.w);
    WS_COUNTS(ws)[k] = 0;
  }
  if (k == 0) *WS_SSE(ws) = 0.f;
}

// ---------------------------------------------------------------- main ----
union SharedU {
  float el[KCHUNK * LDSW];
  struct { float d1[MBLK * 17]; float d2[MBLK * 17]; int i1[MBLK * 17]; } red;
};

__global__ __launch_bounds__(256, 2) void vq_main(const float* __restrict__ z,
                                                  const float* __restrict__ emb,
                                                  void* ws,
                                                  float* __restrict__ out) {
  __shared__ __align__(16) float zl[MBLK * LDSW];
  __shared__ __align__(16) SharedU u;
  __shared__ float e2l[KCODE];
  __shared__ int   win[MBLK];
  __shared__ float ssew[4];

  const int tid = threadIdx.x;
  const int r0  = blockIdx.x * MBLK;
  const int rg  = tid >> 4;   // 0..15 : rows rg + 16*i
  const int cg  = tid & 15;   // 0..15 : codes cg + 16*j (per strip)

  // stage z tile (128 rows x 64 d) into padded LDS
  const float4* zg = (const float4*)(z + (size_t)r0 * DIM);
#pragma unroll
  for (int k = 0; k < 8; ++k) {
    int f = tid + k * 256;             // 0..2047 float4 slots
    int row = f >> 4, c4 = f & 15;
    *(float4*)&zl[row * LDSW + c4 * 4] = zg[f];
  }
  // stage e2 (1024 floats)
  *(float4*)&e2l[tid * 4] = ((const float4*)WS_E2(ws))[tid];

  float b1[8], b2[8]; int i1[8];
#pragma unroll
  for (int i = 0; i < 8; ++i) { b1[i] = 3.4e38f; b2[i] = 3.4e38f; i1[i] = 0; }

  for (int s = 0; s < NSTRIP; ++s) {
    __syncthreads();   // prior readers of u.el done (no-op cost on s==0)
    const float4* eg = (const float4*)(emb + (size_t)(s * KCHUNK) * DIM);
#pragma unroll
    for (int k = 0; k < 8; ++k) {
      int f = tid + k * 256;
      int row = f >> 4, c4 = f & 15;
      *(float4*)&u.el[row * LDSW + c4 * 4] = eg[f];
    }
    __syncthreads();   // u.el ready (s==0: zl, e2l also ready)

    float e2r[8];
#pragma unroll
    for (int j = 0; j < 8; ++j) e2r[j] = e2l[s * KCHUNK + cg + 16 * j];

    float acc[8][8];
#pragma unroll
    for (int i = 0; i < 8; ++i)
#pragma unroll
      for (int j = 0; j < 8; ++j) acc[i][j] = 0.f;

#pragma unroll 2
    for (int d4 = 0; d4 < 16; ++d4) {
      float4 zv[8], ev[8];
#pragma unroll
      for (int i = 0; i < 8; ++i)
        zv[i] = *(const float4*)&zl[(rg + 16 * i) * LDSW + d4 * 4];
#pragma unroll
      for (int j = 0; j < 8; ++j)
        ev[j] = *(const float4*)&u.el[(cg + 16 * j) * LDSW + d4 * 4];
#pragma unroll
      for (int i = 0; i < 8; ++i)
#pragma unroll
        for (int j = 0; j < 8; ++j) {
          acc[i][j] = fmaf(zv[i].x, ev[j].x, acc[i][j]);
          acc[i][j] = fmaf(zv[i].y, ev[j].y, acc[i][j]);
          acc[i][j] = fmaf(zv[i].z, ev[j].z, acc[i][j]);
          acc[i][j] = fmaf(zv[i].w, ev[j].w, acc[i][j]);
        }
    }

    // top-2 running update (codes ascend: strips asc, j asc -> strict < keeps lowest idx)
#pragma unroll
    for (int j = 0; j < 8; ++j) {
      int code = s * KCHUNK + cg + 16 * j;
#pragma unroll
      for (int i = 0; i < 8; ++i) {
        float dist = fmaf(-2.0f, acc[i][j], e2r[j]);  // ||z||^2 dropped (row-const)
        bool  lt   = dist < b1[i];
        float nb2  = lt ? b1[i] : fminf(b2[i], dist);
        if (lt) { b1[i] = dist; i1[i] = code; }
        b2[i] = nb2;
      }
    }
  }

  __syncthreads();   // all reads of u.el done; reuse union as reduction buffers
#pragma unroll
  for (int i = 0; i < 8; ++i) {
    int row = rg + 16 * i;
    u.red.d1[row * 17 + cg] = b1[i];
    u.red.d2[row * 17 + cg] = b2[i];
    u.red.i1[row * 17 + cg] = i1[i];
  }
  __syncthreads();

  if (tid < MBLK) {
    int row = tid;
    float B1 = 3.4e38f, B2 = 3.4e38f; int I1 = 0x7fffffff;
    for (int c = 0; c < 16; ++c) {
      float d1v = u.red.d1[row * 17 + c];
      float d2v = u.red.d2[row * 17 + c];
      int   idx = u.red.i1[row * 17 + c];
      if (d1v < B1 || (d1v == B1 && idx < I1)) {
        B2 = fminf(B1, d2v);
        B1 = d1v; I1 = idx;
      } else {
        B2 = fminf(B2, d1v);
      }
    }
    int grow = r0 + row;
    bool flg = (B2 - B1) < TAU;            // uncertified argmin -> fp64 fixup
    WS_FLAGS(ws)[grow] = flg ? 1 : 0;
    win[row] = flg ? -1 : I1;
    if (!flg) atomicAdd(&WS_COUNTS(ws)[I1], 1);
  }
  __syncthreads();

  // gather + quantized_st + sse partial (2 threads per row; skip flagged rows)
  float ssep = 0.f;
  {
    int row = tid >> 1, half = tid & 1;
    int w = win[row];
    if (w >= 0) {
      const float4* ev  = (const float4*)(emb + (size_t)w * DIM) + half * 8;
      const float4* zv4 = (const float4*)&zl[row * LDSW] + half * 8;
      float4* og = (float4*)(out + (size_t)(r0 + row) * DIM) + half * 8;
#pragma unroll
      for (int k = 0; k < 8; ++k) {
        float4 e = ev[k], zz = zv4[k];
        float4 q;
        q.x = zz.x + (e.x - zz.x); q.y = zz.y + (e.y - zz.y);
        q.z = zz.z + (e.z - zz.z); q.w = zz.w + (e.w - zz.w);
        og[k] = q;
        float dx = zz.x - e.x, dy = zz.y - e.y, dz = zz.z - e.z, dw = zz.w - e.w;
        ssep += dx * dx + dy * dy + dz * dz + dw * dw;
      }
    }
  }
  for (int off = 32; off; off >>= 1) ssep += __shfl_down(ssep, off, 64);
  if ((tid & 63) == 0) ssew[tid >> 6] = ssep;
  __syncthreads();
  if (tid == 0) atomicAdd(WS_SSE(ws), (ssew[0] + ssew[1]) + (ssew[2] + ssew[3]));
}

// --------------------------------------------------------------- fixup ----
// fp64 full re-score of flagged rows; writes their out rows, counts, sse.
__global__ __launch_bounds__(256) void vq_fixup(const float* __restrict__ z,
                                                const float* __restrict__ emb,
                                                void* ws,
                                                float* __restrict__ out) {
  const int CH = NROWS / 1024;   // 64 rows per block, grid = 1024
  int base = blockIdx.x * CH;
  int tid = threadIdx.x;

  __shared__ int list[CH];
  __shared__ int nlist;
  __shared__ __align__(16) float zrow[DIM];
  __shared__ double rd[256];
  __shared__ int    ri[256];

  if (tid == 0) nlist = 0;
  __syncthreads();
  if (tid < CH && WS_FLAGS(ws)[base + tid]) {
    int p = atomicAdd(&nlist, 1);
    list[p] = base + tid;
  }
  __syncthreads();
  int n = nlist;

  for (int q = 0; q < n; ++q) {
    int row = list[q];
    if (tid < 16) *(float4*)&zrow[tid * 4] = ((const float4*)(z + (size_t)row * DIM))[tid];
    __syncthreads();

    double bd = 1e300; int bi = 0x7fffffff;
    for (int c = tid; c < KCODE; c += 256) {
      const float4* e4 = (const float4*)(emb + (size_t)c * DIM);
      double dot = 0.0, e2 = 0.0;
#pragma unroll
      for (int t = 0; t < 16; ++t) {
        float4 v = e4[t];
        float4 zz = *(const float4*)&zrow[t * 4];
        dot = fma((double)zz.x, (double)v.x, dot);
        dot = fma((double)zz.y, (double)v.y, dot);
        dot = fma((double)zz.z, (double)v.z, dot);
        dot = fma((double)zz.w, (double)v.w, dot);
        e2  = fma((double)v.x, (double)v.x, e2);
        e2  = fma((double)v.y, (double)v.y, e2);
        e2  = fma((double)v.z, (double)v.z, e2);
        e2  = fma((double)v.w, (double)v.w, e2);
      }
      double dist = e2 - 2.0 * dot;       // ||z||^2 row-constant, dropped
      if (dist < bd || (dist == bd && c < bi)) { bd = dist; bi = c; }
    }
    rd[tid] = bd; ri[tid] = bi;
    __syncthreads();
    for (int st = 128; st; st >>= 1) {
      if (tid < st) {
        double od = rd[tid + st]; int oi = ri[tid + st];
        if (od < rd[tid] || (od == rd[tid] && oi < ri[tid])) { rd[tid] = od; ri[tid] = oi; }
      }
      __syncthreads();
    }
    int w = ri[0];
    if (tid < 16) {
      float4 e  = ((const float4*)(emb + (size_t)w * DIM))[tid];
      float4 zz = *(const float4*)&zrow[tid * 4];
      float4 qv;
      qv.x = zz.x + (e.x - zz.x); qv.y = zz.y + (e.y - zz.y);
      qv.z = zz.z + (e.z - zz.z); qv.w = zz.w + (e.w - zz.w);
      ((float4*)(out + (size_t)row * DIM))[tid] = qv;
      float dx = zz.x - e.x, dy = zz.y - e.y, dz = zz.z - e.z, dw = zz.w - e.w;
      float part = dx * dx + dy * dy + dz * dz + dw * dw;
      part += __shfl_down(part, 8, 64);
      part += __shfl_down(part, 4, 64);
      part += __shfl_down(part, 2, 64);
      part += __shfl_down(part, 1, 64);
      if (tid == 0) {
        atomicAdd(WS_SSE(ws), part);
        atomicAdd(&WS_COUNTS(ws)[w], 1);
      }
    }
    __syncthreads();  // protect zrow before next q
  }
}

// ------------------------------------------------------------ finalize ----
__global__ __launch_bounds__(256) void vq_finalize(void* ws, float* __restrict__ out) {
  int tid = threadIdx.x;
  __shared__ float w4[4];
  float part = 0.f;
  for (int c = tid; c < KCODE; c += 256) {
    float p = (float)WS_COUNTS(ws)[c] * (1.0f / (float)NROWS);
    part += p * logf(p + 1e-10f);
  }
  for (int off = 32; off; off >>= 1) part += __shfl_down(part, off, 64);
  if ((tid & 63) == 0) w4[tid >> 6] = part;
  __syncthreads();
  if (tid == 0) {
    float ent = (w4[0] + w4[1]) + (w4[2] + w4[3]);
    float perp = expf(-ent);
    perp = fminf(perp, (float)KCODE);
    if (!isfinite(perp)) perp = 0.f;
    out[(size_t)NROWS * DIM]     = 0.25f * (*WS_SSE(ws)) / (float)((size_t)NROWS * DIM);
    out[(size_t)NROWS * DIM + 1] = perp;
  }
}

extern "C" void kernel_launch(void* const* d_in, const int* in_sizes, int n_in,
                              void* d_out, int out_size, void* d_ws, size_t ws_size,
                              hipStream_t stream) {
  const float* z   = (const float*)d_in[0];
  const float* emb = (const float*)d_in[1];
  float* out = (float*)d_out;
  (void)in_sizes; (void)n_in; (void)out_size; (void)ws_size;

  vq_init    <<<4,    256, 0, stream>>>(emb, d_ws);
  vq_main    <<<NROWS / MBLK, 256, 0, stream>>>(z, emb, d_ws, out);
  vq_fixup   <<<1024, 256, 0, stream>>>(z, emb, d_ws, out);
  vq_finalize<<<1,    256, 0, stream>>>(d_ws, out);
}

// Round 2
// 108.472 us; speedup vs baseline: 1.5558x; 1.5558x over previous
//
#include <hip/hip_runtime.h>
#include <math.h>

#define NROWS 65536      // B*T
#define DIM   64
#define KCODE 1024
#define TAU_M 2e-3f      // margin threshold in m-units (dist gap = 2x this)

typedef __attribute__((ext_vector_type(8))) short short8;
typedef __bf16 bf16_t;
typedef bf16_t bf16x8 __attribute__((ext_vector_type(8)));
typedef __attribute__((ext_vector_type(4))) float f32x4;

union B8 { bf16x8 v; short8 s; ushort u[8]; };

// ws layout (bytes):
//   [0      .. 262143]  ushort emb_frag  (1024 codes x 64 dims x {hi,lo}) in MFMA B order
//   [262144 .. 266239]  float  e2h[1024]  = -||e||^2 / 2
//   [266240 .. 270335]  int    counts[1024]
//   [270336 .. 270339]  float  sse
//   [270352 .. 335887]  uchar  flags[NROWS]
#define WS_EMBF(ws)   ((ushort*)(ws))
#define WS_E2H(ws)    ((float*)((char*)(ws) + 262144))
#define WS_COUNTS(ws) ((int*)((char*)(ws) + 266240))
#define WS_SSE(ws)    ((float*)((char*)(ws) + 270336))
#define WS_FLAGS(ws)  ((unsigned char*)(ws) + 270352)

__device__ __forceinline__ ushort f2bf(float x) {
  unsigned u = __float_as_uint(x);
  u += 0x7FFFu + ((u >> 16) & 1u);           // RNE
  return (ushort)(u >> 16);
}
__device__ __forceinline__ float bf2f(ushort h) {
  return __uint_as_float(((unsigned)h) << 16);
}

// ---------------------------------------------------------------- init ----
// grid 1024 blocks x 64 threads: block = code, thread = dim.
// Writes emb_frag (hi/lo bf16 in B-fragment lane order), e2h, zeros counts/sse.
__global__ __launch_bounds__(64) void vq_init(const float* __restrict__ emb, void* ws) {
  int k = blockIdx.x, d = threadIdx.x;
  float x = emb[k * DIM + d];
  ushort hs = f2bf(x);
  ushort ls = f2bf(x - bf2f(hs));
  // B-fragment order: strip(64 codes) -> tile(16 codes) -> frag(ks*2+h, 1KB) -> lane*16B -> e*2B
  int strip = k >> 6, tile = (k >> 4) & 3, colv = k & 15;
  int ks = d >> 5, kq = (d >> 3) & 3, e = d & 7;
  int lane = colv + kq * 16;
  size_t byte = (size_t)strip * 16384 + (size_t)tile * 4096 + (size_t)(ks * 2) * 1024
              + (size_t)lane * 16 + (size_t)e * 2;
  ushort* uf = WS_EMBF(ws);
  uf[byte >> 1] = hs;
  uf[(byte >> 1) + 512] = ls;                // lo fragment = +1024 bytes
  float s = x * x;
#pragma unroll
  for (int off = 32; off; off >>= 1) s += __shfl_down(s, off, 64);
  if (d == 0) {
    WS_E2H(ws)[k] = -0.5f * s;
    WS_COUNTS(ws)[k] = 0;
    if (k == 0) *WS_SSE(ws) = 0.f;
  }
}

// ---------------------------------------------------------------- main ----
// 256 threads = 4 waves; wave owns 64 rows; block = 256 rows; grid = 256 (1 block/CU).
__global__ __launch_bounds__(256, 1) void vq_main(const float* __restrict__ z,
                                                  const float* __restrict__ emb,
                                                  void* ws,
                                                  float* __restrict__ outp) {
  __shared__ __align__(16) int4 ebuf[2][1024];   // 2 x 16KB strip buffers (64 codes)
  __shared__ float e2s[KCODE];                   // 4KB, staged once
  __shared__ int   win[256];
  __shared__ float ssew[4];

  const int tid  = threadIdx.x;
  const int lane = tid & 63, w = tid >> 6;
  const int col  = lane & 15, kq = lane >> 4;
  const int rowbase = blockIdx.x * 256 + w * 64;

  // stage e2h -> LDS (4KB)
  ((float4*)e2s)[tid] = ((const float4*)WS_E2H(ws))[tid];

  // A fragments: 4 row-groups x 2 ksteps, hi+lo, held in registers all kernel
  B8 ah[4][2], al[4][2];
#pragma unroll
  for (int g = 0; g < 4; ++g) {
    int row = rowbase + g * 16 + col;
    const float* zr = z + (size_t)row * DIM;
#pragma unroll
    for (int ks = 0; ks < 2; ++ks) {
      const float4* p = (const float4*)(zr + ks * 32 + kq * 8);
      float4 x0 = p[0], x1 = p[1];
      float vv[8] = {x0.x, x0.y, x0.z, x0.w, x1.x, x1.y, x1.z, x1.w};
#pragma unroll
      for (int e = 0; e < 8; ++e) {
        ushort hs = f2bf(vv[e]);
        ah[g][ks].u[e] = hs;
        al[g][ks].u[e] = f2bf(vv[e] - bf2f(hs));
      }
    }
  }

  float b1[16], b2[16]; int i1[16];              // top-2 of m = z.e - e^2/2 (max form)
#pragma unroll
  for (int q = 0; q < 16; ++q) { b1[q] = -3.4e38f; b2[q] = -3.4e38f; i1[q] = 0; }

  const int4* ef4 = (const int4*)WS_EMBF(ws);
  // prefetch strip 0 into registers (T14: issue-early)
  int4 V0, V1, V2, V3;
  {
    const int4* sp = ef4 + tid;
    V0 = sp[0]; V1 = sp[256]; V2 = sp[512]; V3 = sp[768];
  }

  for (int s = 0; s < 16; ++s) {
    // write staged strip (lane-linear 16B: conflict-free), prefetch next
    int4* db = &ebuf[s & 1][0];
    db[tid] = V0; db[tid + 256] = V1; db[tid + 512] = V2; db[tid + 768] = V3;
    if (s < 15) {
      const int4* sp = ef4 + (s + 1) * 1024 + tid;
      V0 = sp[0]; V1 = sp[256]; V2 = sp[512]; V3 = sp[768];
    }
    __syncthreads();

    const short8* bp = (const short8*)&ebuf[s & 1][0];
#pragma unroll
    for (int t = 0; t < 4; ++t) {
      B8 bh0, bl0, bh1, bl1;
      bh0.s = bp[(t * 4 + 0) * 64 + lane];
      bl0.s = bp[(t * 4 + 1) * 64 + lane];
      bh1.s = bp[(t * 4 + 2) * 64 + lane];
      bl1.s = bp[(t * 4 + 3) * 64 + lane];
      float c = e2s[s * 64 + t * 16 + col];
      f32x4 cc = {c, c, c, c};
      int gt = s * 4 + t;
#pragma unroll
      for (int g = 0; g < 4; ++g) {
        f32x4 a = __builtin_amdgcn_mfma_f32_16x16x32_bf16(ah[g][0].v, bh0.v, cc, 0, 0, 0);
        a = __builtin_amdgcn_mfma_f32_16x16x32_bf16(al[g][0].v, bh0.v, a, 0, 0, 0);
        a = __builtin_amdgcn_mfma_f32_16x16x32_bf16(ah[g][0].v, bl0.v, a, 0, 0, 0);
        a = __builtin_amdgcn_mfma_f32_16x16x32_bf16(ah[g][1].v, bh1.v, a, 0, 0, 0);
        a = __builtin_amdgcn_mfma_f32_16x16x32_bf16(al[g][1].v, bh1.v, a, 0, 0, 0);
        a = __builtin_amdgcn_mfma_f32_16x16x32_bf16(ah[g][1].v, bl1.v, a, 0, 0, 0);
#pragma unroll
        for (int r = 0; r < 4; ++r) {
          float m = a[r]; int q = g * 4 + r;
          b2[q] = fmaxf(b2[q], fminf(m, b1[q]));
          bool better = m > b1[q];
          b1[q] = better ? m : b1[q];
          i1[q] = better ? gt : i1[q];
        }
      }
    }
  }

  // cross-lane top-2 merge over the 16 column-lanes (lanes sharing l>>4)
#pragma unroll
  for (int q = 0; q < 16; ++q) {
    float m1 = b1[q], m2 = b2[q];
    int c1 = i1[q] * 16 + col;
#pragma unroll
    for (int off = 1; off < 16; off <<= 1) {
      float om1 = __shfl_xor(m1, off, 64);
      float om2 = __shfl_xor(m2, off, 64);
      int   oc1 = __shfl_xor(c1, off, 64);
      bool take = (om1 > m1) || (om1 == m1 && oc1 < c1);
      m2 = fmaxf(fminf(m1, om1), take ? om2 : m2);
      m1 = take ? om1 : m1;
      c1 = take ? oc1 : c1;
    }
    if (col == 0) {
      int lrow = w * 64 + (q >> 2) * 16 + kq * 4 + (q & 3);
      int grow = blockIdx.x * 256 + lrow;
      bool flg = (m1 - m2) < TAU_M;            // uncertified -> fp64 fixup
      WS_FLAGS(ws)[grow] = flg ? 1 : 0;
      win[lrow] = flg ? -1 : c1;
      if (!flg) atomicAdd(&WS_COUNTS(ws)[c1], 1);
    }
  }
  __syncthreads();

  // gather + quantized_st + sse (4 threads/row, coalesced; skip flagged rows)
  float ssep = 0.f;
#pragma unroll
  for (int pass = 0; pass < 4; ++pass) {
    int lrow = pass * 64 + (tid >> 2);
    int qtr  = tid & 3;
    int wv = win[lrow];
    if (wv >= 0) {
      size_t grow = (size_t)blockIdx.x * 256 + lrow;
      const float4* ep = (const float4*)(emb + (size_t)wv * DIM) + qtr * 4;
      const float4* zp = (const float4*)(z + grow * DIM) + qtr * 4;
      float4* op = (float4*)(outp + grow * DIM) + qtr * 4;
#pragma unroll
      for (int j = 0; j < 4; ++j) {
        float4 e = ep[j], zz = zp[j];
        float4 qv;
        qv.x = zz.x + (e.x - zz.x); qv.y = zz.y + (e.y - zz.y);
        qv.z = zz.z + (e.z - zz.z); qv.w = zz.w + (e.w - zz.w);
        op[j] = qv;
        float dx = zz.x - e.x, dy = zz.y - e.y, dz = zz.z - e.z, dw = zz.w - e.w;
        ssep += dx * dx + dy * dy + dz * dz + dw * dw;
      }
    }
  }
  for (int off = 32; off; off >>= 1) ssep += __shfl_down(ssep, off, 64);
  if (lane == 0) ssew[w] = ssep;
  __syncthreads();
  if (tid == 0) atomicAdd(WS_SSE(ws), (ssew[0] + ssew[1]) + (ssew[2] + ssew[3]));
}

// --------------------------------------------------------------- fixup ----
// fp64 full re-score of flagged rows; writes their out rows, counts, sse.
__global__ __launch_bounds__(256) void vq_fixup(const float* __restrict__ z,
                                                const float* __restrict__ emb,
                                                void* ws,
                                                float* __restrict__ out) {
  const int CH = NROWS / 1024;   // 64 rows per block, grid = 1024
  int base = blockIdx.x * CH;
  int tid = threadIdx.x;

  __shared__ int list[CH];
  __shared__ int nlist;
  __shared__ __align__(16) float zrow[DIM];
  __shared__ double rd[256];
  __shared__ int    ri[256];

  if (tid == 0) nlist = 0;
  __syncthreads();
  if (tid < CH && WS_FLAGS(ws)[base + tid]) {
    int p = atomicAdd(&nlist, 1);
    list[p] = base + tid;
  }
  __syncthreads();
  int n = nlist;

  for (int q = 0; q < n; ++q) {
    int row = list[q];
    if (tid < 16) *(float4*)&zrow[tid * 4] = ((const float4*)(z + (size_t)row * DIM))[tid];
    __syncthreads();

    double bd = 1e300; int bi = 0x7fffffff;
    for (int c = tid; c < KCODE; c += 256) {
      const float4* e4 = (const float4*)(emb + (size_t)c * DIM);
      double dot = 0.0, e2 = 0.0;
#pragma unroll
      for (int t = 0; t < 16; ++t) {
        float4 v = e4[t];
        float4 zz = *(const float4*)&zrow[t * 4];
        dot = fma((double)zz.x, (double)v.x, dot);
        dot = fma((double)zz.y, (double)v.y, dot);
        dot = fma((double)zz.z, (double)v.z, dot);
        dot = fma((double)zz.w, (double)v.w, dot);
        e2  = fma((double)v.x, (double)v.x, e2);
        e2  = fma((double)v.y, (double)v.y, e2);
        e2  = fma((double)v.z, (double)v.z, e2);
        e2  = fma((double)v.w, (double)v.w, e2);
      }
      double dist = e2 - 2.0 * dot;
      if (dist < bd || (dist == bd && c < bi)) { bd = dist; bi = c; }
    }
    rd[tid] = bd; ri[tid] = bi;
    __syncthreads();
    for (int st = 128; st; st >>= 1) {
      if (tid < st) {
        double od = rd[tid + st]; int oi = ri[tid + st];
        if (od < rd[tid] || (od == rd[tid] && oi < ri[tid])) { rd[tid] = od; ri[tid] = oi; }
      }
      __syncthreads();
    }
    int wi = ri[0];
    if (tid < 16) {
      float4 e  = ((const float4*)(emb + (size_t)wi * DIM))[tid];
      float4 zz = *(const float4*)&zrow[tid * 4];
      float4 qv;
      qv.x = zz.x + (e.x - zz.x); qv.y = zz.y + (e.y - zz.y);
      qv.z = zz.z + (e.z - zz.z); qv.w = zz.w + (e.w - zz.w);
      ((float4*)(out + (size_t)row * DIM))[tid] = qv;
      float dx = zz.x - e.x, dy = zz.y - e.y, dz = zz.z - e.z, dw = zz.w - e.w;
      float part = dx * dx + dy * dy + dz * dz + dw * dw;
      part += __shfl_down(part, 8, 64);
      part += __shfl_down(part, 4, 64);
      part += __shfl_down(part, 2, 64);
      part += __shfl_down(part, 1, 64);
      if (tid == 0) {
        atomicAdd(WS_SSE(ws), part);
        atomicAdd(&WS_COUNTS(ws)[wi], 1);
      }
    }
    __syncthreads();
  }
}

// ------------------------------------------------------------ finalize ----
__global__ __launch_bounds__(256) void vq_finalize(void* ws, float* __restrict__ out) {
  int tid = threadIdx.x;
  __shared__ float w4[4];
  float part = 0.f;
  for (int c = tid; c < KCODE; c += 256) {
    float p = (float)WS_COUNTS(ws)[c] * (1.0f / (float)NROWS);
    part += p * logf(p + 1e-10f);
  }
  for (int off = 32; off; off >>= 1) part += __shfl_down(part, off, 64);
  if ((tid & 63) == 0) w4[tid >> 6] = part;
  __syncthreads();
  if (tid == 0) {
    float ent = (w4[0] + w4[1]) + (w4[2] + w4[3]);
    float perp = expf(-ent);
    perp = fminf(perp, (float)KCODE);
    if (!isfinite(perp)) perp = 0.f;
    out[(size_t)NROWS * DIM]     = 0.25f * (*WS_SSE(ws)) / (float)((size_t)NROWS * DIM);
    out[(size_t)NROWS * DIM + 1] = perp;
  }
}

extern "C" void kernel_launch(void* const* d_in, const int* in_sizes, int n_in,
                              void* d_out, int out_size, void* d_ws, size_t ws_size,
                              hipStream_t stream) {
  const float* z   = (const float*)d_in[0];
  const float* emb = (const float*)d_in[1];
  float* out = (float*)d_out;
  (void)in_sizes; (void)n_in; (void)out_size; (void)ws_size;

  vq_init    <<<KCODE, 64,  0, stream>>>(emb, d_ws);
  vq_main    <<<NROWS / 256, 256, 0, stream>>>(z, emb, d_ws, out);
  vq_fixup   <<<1024, 256, 0, stream>>>(z, emb, d_ws, out);
  vq_finalize<<<1,    256, 0, stream>>>(d_ws, out);
}